// Round 4
// baseline (200.594 us; speedup 1.0000x reference)
//
#include <hip/hip_runtime.h>

#define B_ROWS 524288
#define D_DIM 64
#define GRID 2048
#define BLOCK 256
// waves total = GRID*BLOCK/64 = 8192; rows per wave-iter = 16 -> 131072/iter
#define ROWS_PER_ITER ((GRID * BLOCK / 64) * 16)
#define N_ITERS (B_ROWS / ROWS_PER_ITER)   // = 4, compile-time

// 4 lanes per row; all 16 x-loads (4 iters x 4 dwordx4) + 4 label loads hoisted
// ahead of all compute so one wave has 16 outstanding 16B loads (covers full
// L3/HBM latency). 2-stage butterfly row reduction; epilogue duplicated on the
// 4 lanes of a group (same-address gathers broadcast); block partial -> d_ws.
__global__ __launch_bounds__(BLOCK) void mcl_main(
    const float* __restrict__ x,
    const int* __restrict__ labels,
    const float* __restrict__ lin_w,
    const float* __restrict__ lin_b,
    const float* __restrict__ linear_p,   // (1000,1,3)
    const float* __restrict__ bias_p,     // (1000,3)
    const float* __restrict__ centers,    // (1000,3,1)
    float* __restrict__ partials)
{
    const int tid        = blockIdx.x * BLOCK + threadIdx.x;
    const int lane       = threadIdx.x & 63;
    const int sub        = lane & 3;        // position within 4-lane row group
    const int rowInWave  = lane >> 2;       // 0..15
    const int waveGlobal = tid >> 6;
    const int row0       = waveGlobal * 16 + rowInWave;

    const float4 lw0 = ((const float4*)lin_w)[sub + 0];
    const float4 lw1 = ((const float4*)lin_w)[sub + 4];
    const float4 lw2 = ((const float4*)lin_w)[sub + 8];
    const float4 lw3 = ((const float4*)lin_w)[sub + 12];
    const float  lb  = lin_b[0];

    // ---- hoisted loads: 16 dwordx4 + 4 labels, all independent ----
    float4 xa[N_ITERS][4];
    int    lab[N_ITERS];
    #pragma unroll
    for (int it = 0; it < N_ITERS; ++it) {
        const int r = row0 + it * ROWS_PER_ITER;
        const float4* xr = (const float4*)(x + (size_t)r * D_DIM);
        xa[it][0] = xr[sub + 0];
        xa[it][1] = xr[sub + 4];
        xa[it][2] = xr[sub + 8];
        xa[it][3] = xr[sub + 12];
        lab[it]   = labels[r];
    }

    float acc = 0.0f;

    #pragma unroll
    for (int it = 0; it < N_ITERS; ++it) {
        const float4 x0 = xa[it][0], x1 = xa[it][1], x2 = xa[it][2], x3 = xa[it][3];
        const int    lb_i = lab[it];

        // issue table gathers early (independent of the shfl chain below)
        const float p0 = linear_p[lb_i * 3 + 0];
        const float p1 = linear_p[lb_i * 3 + 1];
        const float p2 = linear_p[lb_i * 3 + 2];
        const float b0 = bias_p[lb_i * 3 + 0];
        const float b1 = bias_p[lb_i * 3 + 1];
        const float b2 = bias_p[lb_i * 3 + 2];
        const float c0 = centers[lb_i * 3 + 0];
        const float c1 = centers[lb_i * 3 + 1];
        const float c2 = centers[lb_i * 3 + 2];

        float sd = x0.x*lw0.x + x0.y*lw0.y + x0.z*lw0.z + x0.w*lw0.w
                 + x1.x*lw1.x + x1.y*lw1.y + x1.z*lw1.z + x1.w*lw1.w
                 + x2.x*lw2.x + x2.y*lw2.y + x2.z*lw2.z + x2.w*lw2.w
                 + x3.x*lw3.x + x3.y*lw3.y + x3.z*lw3.z + x3.w*lw3.w;
        float ss = (x0.x + x0.y + x0.z + x0.w) + (x1.x + x1.y + x1.z + x1.w)
                 + (x2.x + x2.y + x2.z + x2.w) + (x3.x + x3.y + x3.z + x3.w);
        float sq = x0.x*x0.x + x0.y*x0.y + x0.z*x0.z + x0.w*x0.w
                 + x1.x*x1.x + x1.y*x1.y + x1.z*x1.z + x1.w*x1.w
                 + x2.x*x2.x + x2.y*x2.y + x2.z*x2.z + x2.w*x2.w
                 + x3.x*x3.x + x3.y*x3.y + x3.z*x3.z + x3.w*x3.w;

        // 2-stage butterfly within the 4-lane group
        #pragma unroll
        for (int off = 1; off < 4; off <<= 1) {
            sd += __shfl_xor(sd, off, 64);
            ss += __shfl_xor(ss, off, 64);
            sq += __shfl_xor(sq, off, 64);
        }

        const float maps = sd + lb;
        const float l0 = maps * p0 + b0;
        const float l1 = maps * p1 + b1;
        const float l2 = maps * p2 + b2;

        const float m  = fmaxf(l0, fmaxf(l1, l2));
        const float e0 = __expf(l0 - m);
        const float e1 = __expf(l1 - m);
        const float e2 = __expf(l2 - m);
        const float rdenom = __builtin_amdgcn_rcpf(e0 + e1 + e2);

        const float dD = (float)D_DIM;
        const float s0 = sq - 2.0f * c0 * ss + dD * c0 * c0;
        const float s1 = sq - 2.0f * c1 * ss + dD * c1 * c1;
        const float s2 = sq - 2.0f * c2 * ss + dD * c2 * c2;

        acc += (e0 * s0 + e1 * s1 + e2 * s2) * rdenom;
    }

    // wave reduction (each row counted 4x; corrected below)
    #pragma unroll
    for (int off = 1; off < 64; off <<= 1)
        acc += __shfl_xor(acc, off, 64);

    __shared__ float waveSums[BLOCK / 64];
    if (lane == 0) waveSums[threadIdx.x >> 6] = acc;
    __syncthreads();
    if (threadIdx.x == 0) {
        float s = waveSums[0] + waveSums[1] + waveSums[2] + waveSums[3];
        partials[blockIdx.x] = s;   // plain store; reducer kernel consumes
    }
}

// Single-block finalize: sum GRID partials, scale, overwrite out (no init needed).
__global__ __launch_bounds__(BLOCK) void mcl_finalize(
    const float* __restrict__ partials, float* __restrict__ out)
{
    float acc = 0.0f;
    #pragma unroll
    for (int i = threadIdx.x; i < GRID; i += BLOCK)
        acc += partials[i];

    const int lane = threadIdx.x & 63;
    #pragma unroll
    for (int off = 1; off < 64; off <<= 1)
        acc += __shfl_xor(acc, off, 64);

    __shared__ float waveSums[BLOCK / 64];
    if (lane == 0) waveSums[threadIdx.x >> 6] = acc;
    __syncthreads();
    if (threadIdx.x == 0) {
        float s = waveSums[0] + waveSums[1] + waveSums[2] + waveSums[3];
        out[0] = s * (0.25f / (float)B_ROWS);
    }
}

extern "C" void kernel_launch(void* const* d_in, const int* in_sizes, int n_in,
                              void* d_out, int out_size, void* d_ws, size_t ws_size,
                              hipStream_t stream) {
    const float* x        = (const float*)d_in[0];
    const int*   labels   = (const int*)d_in[1];
    const float* lin_w    = (const float*)d_in[2];
    const float* lin_b    = (const float*)d_in[3];
    const float* linear_p = (const float*)d_in[4];
    const float* bias_p   = (const float*)d_in[5];
    const float* centers  = (const float*)d_in[6];
    float* out      = (float*)d_out;
    float* partials = (float*)d_ws;

    mcl_main<<<dim3(GRID), dim3(BLOCK), 0, stream>>>(
        x, labels, lin_w, lin_b, linear_p, bias_p, centers, partials);
    mcl_finalize<<<dim3(1), dim3(BLOCK), 0, stream>>>(partials, out);
}